// Round 1
// baseline (148.211 us; speedup 1.0000x reference)
//
#include <hip/hip_runtime.h>
#include <hip/hip_bf16.h>

// EgoAttentionNetwork: B=8192, E=64, F_IN=7, D=64, H=4, HD=16. fp32 in/out.
// Round 7: multi-wave work-split. Block = 256 threads (4 waves), 4 batches per
// BLOCK (was per wave). Same stages/buffers as round 6, but each stage's tile
// loop is split across the 4 waves:
//   - chain egoL1/egoL2: wave w does ct=w (col slice)
//   - KQ: wave w does head h=w (ctg = 4w..4w+3)
//   - P1: wave w does mt=w (row tile)        [needs w0f[4], own xa only]
//   - P2: wave w does ct=w (col slice)       [needs only w1f[.][w] -> -24 VGPR]
//   - S+softmax: wave i owns batch i (softmax stays lane-local)
//   - pY / o64 / result: wave w does ct=w
// Work per wave drops 316 -> 79 MFMAs with ZERO replication overhead; grid
// stays 2048 blocks -> 8192 waves (vs 2048) = 24-32 waves/CU vs 8. LDS
// 18.3 KB/block -> 8 blocks/CU fits. Pure latency-hiding win.

typedef __attribute__((ext_vector_type(8))) short short8;   // 8 bf16
typedef __attribute__((ext_vector_type(4))) short short4b;  // 4 bf16
typedef __attribute__((ext_vector_type(4))) float f32x4;

#define SY 72          // u16 row stride for LDS buffers

// ws offsets in u16 units (total 33792 u16 = 67584 B)
#define WS_G    0      // [256][64]  G[(h*64+f)][j]
#define WS_EGW0 16384  // [64][8]    ego_w0^T (k<7 real, k=7 zero)
#define WS_EGW1 16896  // [64][64]   ego_w1^T
#define WS_WVT  20992  // [64][64]   Wv^T
#define WS_WCT  25088  // [64][64]   Wc^T
#define WS_W0T  29184  // [64][8]    oth_w0^T
#define WS_W1T  29696  // [64][64]   oth_w1^T

__device__ __forceinline__ short f2bs(float x) {
    __hip_bfloat16 h = __float2bfloat16(x);
    return __builtin_bit_cast(short, h);
}
__device__ __forceinline__ unsigned short f2u(float x) {
    __hip_bfloat16 h = __float2bfloat16(x);
    return __builtin_bit_cast(unsigned short, h);
}
__device__ __forceinline__ short8 ldws8(const unsigned short* p) {
    return *(const short8*)p;   // 16B-aligned -> global_load_dwordx4
}

__global__ void pack_ws(const float* __restrict__ ego_w0, const float* __restrict__ ego_w1,
                        const float* __restrict__ oth_w0, const float* __restrict__ oth_w1,
                        const float* __restrict__ Wk, const float* __restrict__ Wv,
                        const float* __restrict__ Wq, const float* __restrict__ Wc,
                        unsigned short* __restrict__ ws) {
    const int blk = blockIdx.x, t = threadIdx.x;
    if (blk < 256) {
        // G[n=(h*64+f)][j] = sum_d Wq[j][16h+d] * Wk[f][16h+d]
        const int n = blk, h = n >> 6, f = n & 63, j = t;
        float a = 0.f;
#pragma unroll
        for (int d = 0; d < 16; ++d)
            a = fmaf(Wq[j * 64 + h * 16 + d], Wk[f * 64 + h * 16 + d], a);
        ws[WS_G + n * 64 + j] = f2u(a);
    } else {
        const int n = blk - 256, k = t;    // n = output col, k = contraction idx
        ws[WS_EGW1 + n * 64 + k] = f2u(ego_w1[k * 64 + n]);
        ws[WS_WVT  + n * 64 + k] = f2u(Wv[k * 64 + n]);
        ws[WS_WCT  + n * 64 + k] = f2u(Wc[k * 64 + n]);
        ws[WS_W1T  + n * 64 + k] = f2u(oth_w1[k * 64 + n]);
        if (k < 8) {
            ws[WS_EGW0 + n * 8 + k] = (k < 7) ? f2u(ego_w0[k * 64 + n]) : 0;
            ws[WS_W0T  + n * 8 + k] = (k < 7) ? f2u(oth_w0[k * 64 + n]) : 0;
        }
    }
}

__global__ __launch_bounds__(256, 6)
void ego_attn_kernel(const float* __restrict__ x,
                     const float* __restrict__ ego_b0, const float* __restrict__ ego_b1,
                     const float* __restrict__ oth_b0, const float* __restrict__ oth_b1,
                     const unsigned short* __restrict__ ws,
                     float* __restrict__ out)
{
    __shared__ __align__(16) short hy[64 * SY];    // H then Y, row-major bf16
    __shared__ __align__(16) short chainbuf[4 * SY];
    __shared__ __align__(16) short kqb[16 * SY];   // row b*4+h : kq[b][h][f]*0.25
    __shared__ __align__(16) short pa[16 * SY];    // P[h][e] (rows h>=4 = copies)
    __shared__ __align__(16) short py[16 * SY];    // row h*4+b : pY[b][h][f]
    __shared__ __align__(16) short ob[4 * SY];     // o64 rows b
    __shared__ __align__(16) float mbuf[4][64];    // mask col per batch

    const int tid  = threadIdx.x;
    const int w    = tid >> 6;                     // wave id 0..3
    const int lane = tid & 63;
    const int lg = lane >> 4, ln = lane & 15;
    const int gb = blockIdx.x * 4;                 // 4 batches per BLOCK

    const short8 z8 = {0, 0, 0, 0, 0, 0, 0, 0};

    // ---- persistent frags (from ws, 16B vector loads) ----
    short8 w0f[4];                                 // P1 is mt-split: need all ct
#pragma unroll
    for (int ct = 0; ct < 4; ++ct)
        w0f[ct] = (lg == 0) ? ldws8(ws + WS_W0T + (ct * 16 + ln) * 8) : z8;
    short8 w1w[2];                                 // P2 is ct-split: only ct=w
#pragma unroll
    for (int kc = 0; kc < 2; ++kc)
        w1w[kc] = ldws8(ws + WS_W1T + (w * 16 + ln) * 64 + kc * 32 + lg * 8);
    float b0v[4];
#pragma unroll
    for (int ct = 0; ct < 4; ++ct) b0v[ct] = oth_b0[ct * 16 + ln];
    const float b1w  = oth_b1[w * 16 + ln];
    const float eb0w = ego_b0[w * 16 + ln];
    const float eb1w = ego_b1[w * 16 + ln];

    // ================= chain: egoL1 -> egoL2 -> KQ (ct/head split) ==========
    short8 xea = z8;                               // A[m=b][k=i<7] = x_b row 0
    if (lg == 0 && ln < 4) {
        const float* xr = x + (size_t)(gb + ln) * 448;
#pragma unroll
        for (int k = 0; k < 7; ++k) xea[k] = f2bs(xr[k]);
    }
    {   // egoL1, ct = w: Hego slice = relu(x0 @ ego_w0 + b0)
        const short8 bfr = (lg == 0) ? ldws8(ws + WS_EGW0 + (w * 16 + ln) * 8) : z8;
        f32x4 c = {eb0w, eb0w, eb0w, eb0w};
        c = __builtin_amdgcn_mfma_f32_16x16x32_bf16(xea, bfr, c, 0, 0, 0);
        if (lg == 0) {
#pragma unroll
            for (int r = 0; r < 4; ++r)
                chainbuf[r * SY + w * 16 + ln] = f2bs(fmaxf(c[r], 0.f));
        }
    }
    __syncthreads();
    short8 ha[2];
#pragma unroll
    for (int kc = 0; kc < 2; ++kc)
        ha[kc] = *(const short8*)&chainbuf[(ln & 3) * SY + kc * 32 + lg * 8];
    __syncthreads();

    float egoR[4];                                 // ego slice ct=w, row r = batch r
    {   // egoL2, ct = w: Ego = relu(Hego @ ego_w1 + b1)
        f32x4 c = {eb1w, eb1w, eb1w, eb1w};
#pragma unroll
        for (int kc = 0; kc < 2; ++kc) {
            const short8 bfr = ldws8(ws + WS_EGW1 + (w * 16 + ln) * 64 + kc * 32 + lg * 8);
            c = __builtin_amdgcn_mfma_f32_16x16x32_bf16(ha[kc], bfr, c, 0, 0, 0);
        }
#pragma unroll
        for (int r = 0; r < 4; ++r) egoR[r] = fmaxf(c[r], 0.f);   // valid all lg (&3 copies)
        if (lg == 0) {
#pragma unroll
            for (int r = 0; r < 4; ++r)
                chainbuf[r * SY + w * 16 + ln] = f2bs(egoR[r]);
        }
    }
    __syncthreads();
    short8 ea[2];
#pragma unroll
    for (int kc = 0; kc < 2; ++kc)
        ea[kc] = *(const short8*)&chainbuf[(ln & 3) * SY + kc * 32 + lg * 8];

    // KQ: wave w owns head h=w (ctg = 4w+q); fold 0.25 score scale here
#pragma unroll
    for (int q = 0; q < 4; ++q) {
        f32x4 c = {0.f, 0.f, 0.f, 0.f};
#pragma unroll
        for (int kc = 0; kc < 2; ++kc) {
            const short8 bfr = ldws8(ws + WS_G + (w * 64 + q * 16 + ln) * 64 + kc * 32 + lg * 8);
            c = __builtin_amdgcn_mfma_f32_16x16x32_bf16(ea[kc], bfr, c, 0, 0, 0);
        }
        if (lg == 0) {
#pragma unroll
            for (int r = 0; r < 4; ++r)
                kqb[(r * 4 + w) * SY + q * 16 + ln] = f2bs(c[r] * 0.25f);
        }
    }
    // mask columns for all 4 batches (wave w loads batch w)
    mbuf[w][lane] = x[(size_t)(gb + w) * 448 + lane * 7];
    __syncthreads();

    // ================= per-batch: P1, P2, S+softmax, pY ======================
#pragma unroll
    for (int i = 0; i < 4; ++i) {
        const float* xb = x + (size_t)(gb + i) * 448;

        // P1 (mt = w): H = relu(X @ W0 + b0)
        short8 xaw = z8;                           // A[m=e][k<7], rows w*16..
        if (lg == 0) {
            const float* xr = xb + (w * 16 + ln) * 7;
#pragma unroll
            for (int k = 0; k < 7; ++k) xaw[k] = f2bs(xr[k]);
        }
#pragma unroll
        for (int ct = 0; ct < 4; ++ct) {
            f32x4 c = {b0v[ct], b0v[ct], b0v[ct], b0v[ct]};
            c = __builtin_amdgcn_mfma_f32_16x16x32_bf16(xaw, w0f[ct], c, 0, 0, 0);
#pragma unroll
            for (int r = 0; r < 4; ++r)
                hy[(w * 16 + lg * 4 + r) * SY + ct * 16 + ln] = f2bs(fmaxf(c[r], 0.f));
        }
        __syncthreads();

        // P2 (ct = w): Y = relu(H @ W1 + b1); then row 0 <- ego_i
        short8 a2[4][2];
#pragma unroll
        for (int mt = 0; mt < 4; ++mt)
#pragma unroll
            for (int kc = 0; kc < 2; ++kc)
                a2[mt][kc] = *(const short8*)&hy[(mt * 16 + ln) * SY + kc * 32 + lg * 8];
        __syncthreads();
#pragma unroll
        for (int mt = 0; mt < 4; ++mt) {
            f32x4 c = {b1w, b1w, b1w, b1w};
            c = __builtin_amdgcn_mfma_f32_16x16x32_bf16(a2[mt][0], w1w[0], c, 0, 0, 0);
            c = __builtin_amdgcn_mfma_f32_16x16x32_bf16(a2[mt][1], w1w[1], c, 0, 0, 0);
#pragma unroll
            for (int r = 0; r < 4; ++r)
                hy[(mt * 16 + lg * 4 + r) * SY + w * 16 + ln] = f2bs(fmaxf(c[r], 0.f));
        }
        if (lg == 0)
            hy[w * 16 + ln] = f2bs(egoR[i]);       // Y row 0 = ego_i (own col slice)
        __syncthreads();

        // S = Y @ kq_i^T + softmax — owned by wave i (softmax stays lane-local)
        if (w == i) {
            short8 kb[2];
#pragma unroll
            for (int kc = 0; kc < 2; ++kc)
                kb[kc] = *(const short8*)&kqb[(i * 4 + (ln & 3)) * SY + kc * 32 + lg * 8];
            float sv[16];
            float m = -3e38f;
#pragma unroll
            for (int mt = 0; mt < 4; ++mt) {
                f32x4 c = {0.f, 0.f, 0.f, 0.f};
                const short8 ya0 = *(const short8*)&hy[(mt * 16 + ln) * SY + 0 * 32 + lg * 8];
                const short8 ya1 = *(const short8*)&hy[(mt * 16 + ln) * SY + 1 * 32 + lg * 8];
                c = __builtin_amdgcn_mfma_f32_16x16x32_bf16(ya0, kb[0], c, 0, 0, 0);
                c = __builtin_amdgcn_mfma_f32_16x16x32_bf16(ya1, kb[1], c, 0, 0, 0);
                const float4 mk = *(const float4*)&mbuf[i][mt * 16 + lg * 4];
                const float mkv[4] = {mk.x, mk.y, mk.z, mk.w};
#pragma unroll
                for (int r = 0; r < 4; ++r) {
                    float s = c[r];                // 0.25 folded into kqb
                    if (mkv[r] < 0.5f) s = -1e9f;
                    sv[mt * 4 + r] = s;
                    m = fmaxf(m, s);
                }
            }
            m = fmaxf(m, __shfl_xor(m, 16));
            m = fmaxf(m, __shfl_xor(m, 32));
            float sum = 0.f;
#pragma unroll
            for (int k = 0; k < 16; ++k) { sv[k] = __expf(sv[k] - m); sum += sv[k]; }
            sum += __shfl_xor(sum, 16);
            sum += __shfl_xor(sum, 32);
            const float inv = 1.f / sum;
#pragma unroll
            for (int mt = 0; mt < 4; ++mt) {
                short4b pk;
#pragma unroll
                for (int r = 0; r < 4; ++r) pk[r] = f2bs(sv[mt * 4 + r] * inv);
                *(short4b*)&pa[ln * SY + mt * 16 + lg * 4] = pk;   // P[h=ln][e]
            }
        }
        __syncthreads();

        // pY = P @ Y  (ct = w)
        short8 pf[2];
#pragma unroll
        for (int kc = 0; kc < 2; ++kc)
            pf[kc] = *(const short8*)&pa[ln * SY + kc * 32 + lg * 8];
        {
            f32x4 c = {0.f, 0.f, 0.f, 0.f};
#pragma unroll
            for (int kc = 0; kc < 2; ++kc) {
                short8 yv;
#pragma unroll
                for (int j = 0; j < 8; ++j)
                    yv[j] = hy[(kc * 32 + lg * 8 + j) * SY + w * 16 + ln];
                c = __builtin_amdgcn_mfma_f32_16x16x32_bf16(pf[kc], yv, c, 0, 0, 0);
            }
            if (lg == 0) {
#pragma unroll
                for (int r = 0; r < 4; ++r)
                    py[(r * 4 + i) * SY + w * 16 + ln] = f2bs(c[r]);   // [h][b][f]
            }
        }
        __syncthreads();
    }

    // ================= tail: o64 = pY @ Wv (head = w), result (ct = w) ======
    {
        short8 af[2];
#pragma unroll
        for (int kc = 0; kc < 2; ++kc)
            af[kc] = *(const short8*)&py[(w * 4 + (ln & 3)) * SY + kc * 32 + lg * 8];
        f32x4 c = {0.f, 0.f, 0.f, 0.f};
#pragma unroll
        for (int kc = 0; kc < 2; ++kc) {
            const short8 bfr = ldws8(ws + WS_WVT + (w * 16 + ln) * 64 + kc * 32 + lg * 8);
            c = __builtin_amdgcn_mfma_f32_16x16x32_bf16(af[kc], bfr, c, 0, 0, 0);
        }
        if (lg == 0) {
#pragma unroll
            for (int r = 0; r < 4; ++r)
                ob[r * SY + w * 16 + ln] = f2bs(c[r]);
        }
    }
    __syncthreads();
    {
        short8 oa[2];
#pragma unroll
        for (int kc = 0; kc < 2; ++kc)
            oa[kc] = *(const short8*)&ob[(ln & 3) * SY + kc * 32 + lg * 8];
        f32x4 c = {0.f, 0.f, 0.f, 0.f};
#pragma unroll
        for (int kc = 0; kc < 2; ++kc) {
            const short8 bfr = ldws8(ws + WS_WCT + (w * 16 + ln) * 64 + kc * 32 + lg * 8);
            c = __builtin_amdgcn_mfma_f32_16x16x32_bf16(oa[kc], bfr, c, 0, 0, 0);
        }
        if (lg == 0) {
#pragma unroll
            for (int r = 0; r < 4; ++r)
                out[(size_t)(gb + r) * 64 + w * 16 + ln] = (c[r] + egoR[r]) * 0.5f;
        }
    }
}

extern "C" void kernel_launch(void* const* d_in, const int* in_sizes, int n_in,
                              void* d_out, int out_size, void* d_ws, size_t ws_size,
                              hipStream_t stream) {
    const float* x      = (const float*)d_in[0];
    const float* ego_w0 = (const float*)d_in[1];
    const float* ego_b0 = (const float*)d_in[2];
    const float* ego_w1 = (const float*)d_in[3];
    const float* ego_b1 = (const float*)d_in[4];
    const float* oth_w0 = (const float*)d_in[5];
    const float* oth_b0 = (const float*)d_in[6];
    const float* oth_w1 = (const float*)d_in[7];
    const float* oth_b1 = (const float*)d_in[8];
    const float* Wk     = (const float*)d_in[9];
    const float* Wv     = (const float*)d_in[10];
    const float* Wq     = (const float*)d_in[11];
    const float* Wc     = (const float*)d_in[12];

    unsigned short* ws = (unsigned short*)d_ws;   // needs 67584 B
    pack_ws<<<320, 64, 0, stream>>>(ego_w0, ego_w1, oth_w0, oth_w1,
                                    Wk, Wv, Wq, Wc, ws);
    ego_attn_kernel<<<2048, 256, 0, stream>>>(
        x, ego_b0, ego_b1, oth_b0, oth_b1, ws, (float*)d_out);
}

// Round 2
// 122.633 us; speedup vs baseline: 1.2086x; 1.2086x over previous
//
#include <hip/hip_runtime.h>
#include <hip/hip_bf16.h>

// EgoAttentionNetwork: B=8192, E=64, F_IN=7, D=64, H=4, HD=16. fp32 in/out.
// Round 8: round-6 single-wave structure (proven 42 µs/dispatch), minus the
// barrier-drain stalls. A 64-thread block is ONE wave, so __syncthreads()'s
// mandatory "s_waitcnt vmcnt(0) lgkmcnt(0)" drain (~25x per wave) only wastes
// time: cross-lane LDS exchange within a wave needs just compile-time DS
// ordering (asm "memory" clobber) + the HW in-order DS pipe; register deps
// get compiler-inserted lgkmcnt waits. Changes vs round 6:
//   - LDS_FENCE() (s_waitcnt lgkmcnt(0), memory clobber) replaces every
//     __syncthreads(): vmcnt (global loads) stays in flight across stages.
//   - ALL x-dependent data (xa frags for 4 batches, mask columns) prefetched
//     at kernel top -> global latency overlaps the whole ego-chain/KQ phase.
//   - mask staged in mbuf[4][64] (written once, read per batch).

typedef __attribute__((ext_vector_type(8))) short short8;   // 8 bf16
typedef __attribute__((ext_vector_type(4))) short short4b;  // 4 bf16
typedef __attribute__((ext_vector_type(4))) float f32x4;

#define SY 72          // u16 row stride for LDS buffers

// wave-local LDS fence: order DS ops at compile time, drain LDS counter only.
// vmcnt deliberately NOT drained -> global prefetches survive stage crossings.
#define LDS_FENCE() asm volatile("s_waitcnt lgkmcnt(0)" ::: "memory")

// ws offsets in u16 units (total 33792 u16 = 67584 B)
#define WS_G    0      // [256][64]  G[(h*64+f)][j]
#define WS_EGW0 16384  // [64][8]    ego_w0^T (k<7 real, k=7 zero)
#define WS_EGW1 16896  // [64][64]   ego_w1^T
#define WS_WVT  20992  // [64][64]   Wv^T
#define WS_WCT  25088  // [64][64]   Wc^T
#define WS_W0T  29184  // [64][8]    oth_w0^T
#define WS_W1T  29696  // [64][64]   oth_w1^T

__device__ __forceinline__ short f2bs(float x) {
    __hip_bfloat16 h = __float2bfloat16(x);
    return __builtin_bit_cast(short, h);
}
__device__ __forceinline__ unsigned short f2u(float x) {
    __hip_bfloat16 h = __float2bfloat16(x);
    return __builtin_bit_cast(unsigned short, h);
}
__device__ __forceinline__ short8 ldws8(const unsigned short* p) {
    return *(const short8*)p;   // 16B-aligned -> global_load_dwordx4
}

__global__ void pack_ws(const float* __restrict__ ego_w0, const float* __restrict__ ego_w1,
                        const float* __restrict__ oth_w0, const float* __restrict__ oth_w1,
                        const float* __restrict__ Wk, const float* __restrict__ Wv,
                        const float* __restrict__ Wq, const float* __restrict__ Wc,
                        unsigned short* __restrict__ ws) {
    const int blk = blockIdx.x, t = threadIdx.x;
    if (blk < 256) {
        // G[n=(h*64+f)][j] = sum_d Wq[j][16h+d] * Wk[f][16h+d]
        const int n = blk, h = n >> 6, f = n & 63, j = t;
        float a = 0.f;
#pragma unroll
        for (int d = 0; d < 16; ++d)
            a = fmaf(Wq[j * 64 + h * 16 + d], Wk[f * 64 + h * 16 + d], a);
        ws[WS_G + n * 64 + j] = f2u(a);
    } else {
        const int n = blk - 256, k = t;    // n = output col, k = contraction idx
        ws[WS_EGW1 + n * 64 + k] = f2u(ego_w1[k * 64 + n]);
        ws[WS_WVT  + n * 64 + k] = f2u(Wv[k * 64 + n]);
        ws[WS_WCT  + n * 64 + k] = f2u(Wc[k * 64 + n]);
        ws[WS_W1T  + n * 64 + k] = f2u(oth_w1[k * 64 + n]);
        if (k < 8) {
            ws[WS_EGW0 + n * 8 + k] = (k < 7) ? f2u(ego_w0[k * 64 + n]) : 0;
            ws[WS_W0T  + n * 8 + k] = (k < 7) ? f2u(oth_w0[k * 64 + n]) : 0;
        }
    }
}

__global__ __launch_bounds__(64, 2)
void ego_attn_kernel(const float* __restrict__ x,
                     const float* __restrict__ ego_b0, const float* __restrict__ ego_b1,
                     const float* __restrict__ oth_b0, const float* __restrict__ oth_b1,
                     const unsigned short* __restrict__ ws,
                     float* __restrict__ out)
{
    __shared__ __align__(16) short hy[64 * SY];    // H then Y, row-major bf16
    __shared__ __align__(16) short chainbuf[4 * SY];
    __shared__ __align__(16) short kqb[16 * SY];   // row b*4+h : kq[b][h][f]*0.25
    __shared__ __align__(16) short pa[16 * SY];    // P[h][e] (rows h>=4 = copies)
    __shared__ __align__(16) short py[16 * SY];    // row h*4+b : pY[b][h][f]
    __shared__ __align__(16) short ob[4 * SY];     // o64 rows b
    __shared__ __align__(16) float mbuf[4][64];    // mask col per batch

    const int lane = threadIdx.x;
    const int lg = lane >> 4, ln = lane & 15;
    const int gb = blockIdx.x * 4;                 // 4 batches per wave

    const short8 z8 = {0, 0, 0, 0, 0, 0, 0, 0};

    // ---- persistent frags (from ws, 16B vector loads) ----
    short8 w0f[4], w1f[2][4];
#pragma unroll
    for (int ct = 0; ct < 4; ++ct)
        w0f[ct] = (lg == 0) ? ldws8(ws + WS_W0T + (ct * 16 + ln) * 8) : z8;
#pragma unroll
    for (int kc = 0; kc < 2; ++kc)
#pragma unroll
        for (int ct = 0; ct < 4; ++ct)
            w1f[kc][ct] = ldws8(ws + WS_W1T + (ct * 16 + ln) * 64 + kc * 32 + lg * 8);
    float b0v[4], b1v[4], eb0v[4], eb1v[4];
#pragma unroll
    for (int ct = 0; ct < 4; ++ct) {
        b0v[ct]  = oth_b0[ct * 16 + ln];
        b1v[ct]  = oth_b1[ct * 16 + ln];
        eb0v[ct] = ego_b0[ct * 16 + ln];
        eb1v[ct] = ego_b1[ct * 16 + ln];
    }

    // ---- prefetch ALL per-wave x data; latency overlaps chain+KQ below ----
    short8 xab[4][4];                              // [batch][mt], lg==0 rows real
#pragma unroll
    for (int i = 0; i < 4; ++i) {
        const float* xb = x + (size_t)(gb + i) * 448;
        mbuf[i][lane] = xb[lane * 7];              // mask column (e = lane)
#pragma unroll
        for (int mt = 0; mt < 4; ++mt) {
            short8 v = z8;
            if (lg == 0) {
                const float* xr = xb + (mt * 16 + ln) * 7;
#pragma unroll
                for (int k = 0; k < 7; ++k) v[k] = f2bs(xr[k]);
            }
            xab[i][mt] = v;
        }
    }

    // ================= chain: egoL1 -> egoL2 -> KQ (all 4 batches) ==========
    short8 xea = z8;                               // A[m=b][k=i<7] = x_b row 0
    if (lg == 0 && ln < 4) {
        const float* xr = x + (size_t)(gb + ln) * 448;
#pragma unroll
        for (int i = 0; i < 7; ++i) xea[i] = f2bs(xr[i]);
    }
#pragma unroll
    for (int ct = 0; ct < 4; ++ct) {              // Hego = relu(x0 @ ego_w0 + b0)
        const short8 bfr = (lg == 0) ? ldws8(ws + WS_EGW0 + (ct * 16 + ln) * 8) : z8;
        f32x4 c = {eb0v[ct], eb0v[ct], eb0v[ct], eb0v[ct]};
        c = __builtin_amdgcn_mfma_f32_16x16x32_bf16(xea, bfr, c, 0, 0, 0);
        if (lg == 0) {
#pragma unroll
            for (int r = 0; r < 4; ++r)
                chainbuf[r * SY + ct * 16 + ln] = f2bs(fmaxf(c[r], 0.f));
        }
    }
    LDS_FENCE();
    short8 ha[2];
#pragma unroll
    for (int kc = 0; kc < 2; ++kc)
        ha[kc] = *(const short8*)&chainbuf[(ln & 3) * SY + kc * 32 + lg * 8];
    LDS_FENCE();

    float egoR[4][4];                              // Ego (post-relu), C-layout
#pragma unroll
    for (int ct = 0; ct < 4; ++ct) {              // Ego = relu(Hego @ ego_w1 + b1)
        f32x4 c = {eb1v[ct], eb1v[ct], eb1v[ct], eb1v[ct]};
#pragma unroll
        for (int kc = 0; kc < 2; ++kc) {
            const short8 bfr = ldws8(ws + WS_EGW1 + (ct * 16 + ln) * 64 + kc * 32 + lg * 8);
            c = __builtin_amdgcn_mfma_f32_16x16x32_bf16(ha[kc], bfr, c, 0, 0, 0);
        }
#pragma unroll
        for (int r = 0; r < 4; ++r) egoR[ct][r] = fmaxf(c[r], 0.f);
    }
    if (lg == 0) {
#pragma unroll
        for (int ct = 0; ct < 4; ++ct)
#pragma unroll
            for (int r = 0; r < 4; ++r)
                chainbuf[r * SY + ct * 16 + ln] = f2bs(egoR[ct][r]);
    }
    LDS_FENCE();
    short8 ea[2];
#pragma unroll
    for (int kc = 0; kc < 2; ++kc)
        ea[kc] = *(const short8*)&chainbuf[(ln & 3) * SY + kc * 32 + lg * 8];

    // KQ[b][n=(h*64+f)] = sum_j Ego[b][j] G[n][j]; fold 0.25 score scale here
#pragma unroll
    for (int ctg = 0; ctg < 16; ++ctg) {
        f32x4 c = {0.f, 0.f, 0.f, 0.f};
#pragma unroll
        for (int kc = 0; kc < 2; ++kc) {
            const short8 bfr = ldws8(ws + WS_G + (ctg * 16 + ln) * 64 + kc * 32 + lg * 8);
            c = __builtin_amdgcn_mfma_f32_16x16x32_bf16(ea[kc], bfr, c, 0, 0, 0);
        }
        if (lg == 0) {
            const int h = ctg >> 2, fc = (ctg & 3) * 16 + ln;
#pragma unroll
            for (int r = 0; r < 4; ++r)
                kqb[(r * 4 + h) * SY + fc] = f2bs(c[r] * 0.25f);
        }
    }
    LDS_FENCE();

    // ================= per-batch: P1, P2, S+softmax, pY ======================
#pragma unroll
    for (int i = 0; i < 4; ++i) {
        // P1: H = relu(X @ W0 + b0)   (xab prefetched at top)
#pragma unroll
        for (int mt = 0; mt < 4; ++mt)
#pragma unroll
            for (int ct = 0; ct < 4; ++ct) {
                f32x4 c = {b0v[ct], b0v[ct], b0v[ct], b0v[ct]};
                c = __builtin_amdgcn_mfma_f32_16x16x32_bf16(xab[i][mt], w0f[ct], c, 0, 0, 0);
#pragma unroll
                for (int r = 0; r < 4; ++r)
                    hy[(mt * 16 + lg * 4 + r) * SY + ct * 16 + ln] = f2bs(fmaxf(c[r], 0.f));
            }
        LDS_FENCE();
        short8 a2[4][2];
#pragma unroll
        for (int mt = 0; mt < 4; ++mt)
#pragma unroll
            for (int kc = 0; kc < 2; ++kc)
                a2[mt][kc] = *(const short8*)&hy[(mt * 16 + ln) * SY + kc * 32 + lg * 8];
        LDS_FENCE();
        // P2: Y = relu(H @ W1 + b1); then row 0 <- ego
#pragma unroll
        for (int ct = 0; ct < 4; ++ct)
#pragma unroll
            for (int mt = 0; mt < 4; ++mt) {
                f32x4 c = {b1v[ct], b1v[ct], b1v[ct], b1v[ct]};
                c = __builtin_amdgcn_mfma_f32_16x16x32_bf16(a2[mt][0], w1f[0][ct], c, 0, 0, 0);
                c = __builtin_amdgcn_mfma_f32_16x16x32_bf16(a2[mt][1], w1f[1][ct], c, 0, 0, 0);
#pragma unroll
                for (int r = 0; r < 4; ++r)
                    hy[(mt * 16 + lg * 4 + r) * SY + ct * 16 + ln] = f2bs(fmaxf(c[r], 0.f));
            }
        if (lg == 0) {
#pragma unroll
            for (int ct = 0; ct < 4; ++ct)
                hy[ct * 16 + ln] = f2bs(egoR[ct][i]);   // Y row 0 = ego_i
        }
        LDS_FENCE();
        // S = Y @ kq_i^T (N=16: n=h, cols >=4 are copies); softmax per head
        short8 ya[4][2];
#pragma unroll
        for (int mt = 0; mt < 4; ++mt)
#pragma unroll
            for (int kc = 0; kc < 2; ++kc)
                ya[mt][kc] = *(const short8*)&hy[(mt * 16 + ln) * SY + kc * 32 + lg * 8];
        short8 kb[2];
#pragma unroll
        for (int kc = 0; kc < 2; ++kc)
            kb[kc] = *(const short8*)&kqb[(i * 4 + (ln & 3)) * SY + kc * 32 + lg * 8];

        float sv[16];
        float m = -3e38f;
#pragma unroll
        for (int mt = 0; mt < 4; ++mt) {
            f32x4 c = {0.f, 0.f, 0.f, 0.f};
            c = __builtin_amdgcn_mfma_f32_16x16x32_bf16(ya[mt][0], kb[0], c, 0, 0, 0);
            c = __builtin_amdgcn_mfma_f32_16x16x32_bf16(ya[mt][1], kb[1], c, 0, 0, 0);
            const float4 mk = *(const float4*)&mbuf[i][mt * 16 + lg * 4];
            const float mkv[4] = {mk.x, mk.y, mk.z, mk.w};
#pragma unroll
            for (int r = 0; r < 4; ++r) {
                float s = c[r];                          // 0.25 folded into kqb
                if (mkv[r] < 0.5f) s = -1e9f;
                sv[mt * 4 + r] = s;
                m = fmaxf(m, s);
            }
        }
        m = fmaxf(m, __shfl_xor(m, 16));
        m = fmaxf(m, __shfl_xor(m, 32));
        float sum = 0.f;
#pragma unroll
        for (int k = 0; k < 16; ++k) { sv[k] = __expf(sv[k] - m); sum += sv[k]; }
        sum += __shfl_xor(sum, 16);
        sum += __shfl_xor(sum, 32);
        const float inv = 1.f / sum;
#pragma unroll
        for (int mt = 0; mt < 4; ++mt) {
            short4b pk;
#pragma unroll
            for (int r = 0; r < 4; ++r) pk[r] = f2bs(sv[mt * 4 + r] * inv);
            *(short4b*)&pa[ln * SY + mt * 16 + lg * 4] = pk;   // P[h=ln][e]
        }
        LDS_FENCE();
        // pY = P @ Y  (M=16: m=h, rows >=4 copies)
        short8 pf[2];
#pragma unroll
        for (int kc = 0; kc < 2; ++kc)
            pf[kc] = *(const short8*)&pa[ln * SY + kc * 32 + lg * 8];
#pragma unroll
        for (int ct = 0; ct < 4; ++ct) {
            f32x4 c = {0.f, 0.f, 0.f, 0.f};
#pragma unroll
            for (int kc = 0; kc < 2; ++kc) {
                short8 yv;
#pragma unroll
                for (int j = 0; j < 8; ++j)
                    yv[j] = hy[(kc * 32 + lg * 8 + j) * SY + ct * 16 + ln];
                c = __builtin_amdgcn_mfma_f32_16x16x32_bf16(pf[kc], yv, c, 0, 0, 0);
            }
            if (lg == 0) {
#pragma unroll
                for (int r = 0; r < 4; ++r)
                    py[(r * 4 + i) * SY + ct * 16 + ln] = f2bs(c[r]);   // [h][b][f]
            }
        }
        LDS_FENCE();
    }

    // ================= tail: o64 = pY @ Wv (head-sliced), result ============
#pragma unroll
    for (int ct = 0; ct < 4; ++ct) {              // ct = head h; cols 16h..16h+16
        short8 af[2];
#pragma unroll
        for (int kc = 0; kc < 2; ++kc)
            af[kc] = *(const short8*)&py[(ct * 4 + (ln & 3)) * SY + kc * 32 + lg * 8];
        f32x4 c = {0.f, 0.f, 0.f, 0.f};
#pragma unroll
        for (int kc = 0; kc < 2; ++kc) {
            const short8 bfr = ldws8(ws + WS_WVT + (ct * 16 + ln) * 64 + kc * 32 + lg * 8);
            c = __builtin_amdgcn_mfma_f32_16x16x32_bf16(af[kc], bfr, c, 0, 0, 0);
        }
        if (lg == 0) {
#pragma unroll
            for (int r = 0; r < 4; ++r)
                ob[r * SY + ct * 16 + ln] = f2bs(c[r]);
        }
    }
    LDS_FENCE();
    short8 oa[2];
#pragma unroll
    for (int kc = 0; kc < 2; ++kc)
        oa[kc] = *(const short8*)&ob[(ln & 3) * SY + kc * 32 + lg * 8];
#pragma unroll
    for (int ct = 0; ct < 4; ++ct) {              // result = o64 @ Wc + ego, *0.5
        f32x4 c = {0.f, 0.f, 0.f, 0.f};
#pragma unroll
        for (int kc = 0; kc < 2; ++kc) {
            const short8 bfr = ldws8(ws + WS_WCT + (ct * 16 + ln) * 64 + kc * 32 + lg * 8);
            c = __builtin_amdgcn_mfma_f32_16x16x32_bf16(oa[kc], bfr, c, 0, 0, 0);
        }
        if (lg == 0) {
#pragma unroll
            for (int r = 0; r < 4; ++r)
                out[(size_t)(gb + r) * 64 + ct * 16 + ln] = (c[r] + egoR[ct][r]) * 0.5f;
        }
    }
}

extern "C" void kernel_launch(void* const* d_in, const int* in_sizes, int n_in,
                              void* d_out, int out_size, void* d_ws, size_t ws_size,
                              hipStream_t stream) {
    const float* x      = (const float*)d_in[0];
    const float* ego_w0 = (const float*)d_in[1];
    const float* ego_b0 = (const float*)d_in[2];
    const float* ego_w1 = (const float*)d_in[3];
    const float* ego_b1 = (const float*)d_in[4];
    const float* oth_w0 = (const float*)d_in[5];
    const float* oth_b0 = (const float*)d_in[6];
    const float* oth_w1 = (const float*)d_in[7];
    const float* oth_b1 = (const float*)d_in[8];
    const float* Wk     = (const float*)d_in[9];
    const float* Wv     = (const float*)d_in[10];
    const float* Wq     = (const float*)d_in[11];
    const float* Wc     = (const float*)d_in[12];

    unsigned short* ws = (unsigned short*)d_ws;   // needs 67584 B
    pack_ws<<<320, 64, 0, stream>>>(ego_w0, ego_w1, oth_w0, oth_w1,
                                    Wk, Wv, Wq, Wc, ws);
    ego_attn_kernel<<<2048, 64, 0, stream>>>(
        x, ego_b0, ego_b1, oth_b0, oth_b1, ws, (float*)d_out);
}